// Round 1
// baseline (448.935 us; speedup 1.0000x reference)
//
#include <hip/hip_runtime.h>
#include <hip/hip_bf16.h>
#include <math.h>

#define N_TOK 16384
#define D_DIM 2048
#define E_EXP 64
#define NTILES 256   /* N_TOK / 64 */

// ---------------------------------------------------------------------------
// GEMM: part[s][t][e] = sum_{k in split s} x[t][k] * W[e][k]
// grid = NTILES * nsplit blocks, 256 threads.
// Tile: 64 tokens x 64 experts. thread = 4 tokens x 4 experts.
// W chunk (64 x 32 fp32) staged in LDS with float4-slot XOR swizzle.
// x read directly from global (each element consumed exactly once per block).
// ---------------------------------------------------------------------------
__global__ __launch_bounds__(256, 4)
void router_gemm(const float* __restrict__ x, const float* __restrict__ W,
                 float* __restrict__ part, int nsplit, int kper) {
  __shared__ float s_w[64 * 32];
  const int tile  = blockIdx.x % NTILES;
  const int split = blockIdx.x / NTILES;
  const int tid = threadIdx.x;
  const int tx = tid & 15;        // expert lane
  const int ty = tid >> 4;        // token lane (0..15)
  const int k0base = split * kper;
  const int nchunk = kper >> 5;   // chunks of 32

  float acc[4][4];
#pragma unroll
  for (int i = 0; i < 4; ++i)
#pragma unroll
    for (int j = 0; j < 4; ++j) acc[i][j] = 0.f;

  const float* xbase[4];
#pragma unroll
  for (int i = 0; i < 4; ++i)
    xbase[i] = x + (size_t)(tile * 64 + i * 16 + ty) * D_DIM + k0base;

  for (int c = 0; c < nchunk; ++c) {
    const int k0 = k0base + c * 32;
    // cooperative W chunk load: 512 float4, 2 per thread, swizzled store
#pragma unroll
    for (int u = 0; u < 2; ++u) {
      int f = u * 256 + tid;
      int row = f >> 3, slot = f & 7;
      float4 wv = *(const float4*)(W + (size_t)row * D_DIM + k0 + slot * 4);
      int ss = slot ^ (row & 7);
      *(float4*)(s_w + row * 32 + ss * 4) = wv;
    }
    __syncthreads();
#pragma unroll
    for (int s = 0; s < 8; ++s) {
      float4 xv[4], wv[4];
#pragma unroll
      for (int i = 0; i < 4; ++i)
        xv[i] = *(const float4*)(xbase[i] + c * 32 + s * 4);
#pragma unroll
      for (int j = 0; j < 4; ++j)
        wv[j] = *(const float4*)(s_w + (16 * j + tx) * 32 + ((s ^ (tx & 7)) * 4));
#pragma unroll
      for (int i = 0; i < 4; ++i)
#pragma unroll
        for (int j = 0; j < 4; ++j)
          acc[i][j] += xv[i].x * wv[j].x + xv[i].y * wv[j].y +
                       xv[i].z * wv[j].z + xv[i].w * wv[j].w;
    }
    __syncthreads();
  }

#pragma unroll
  for (int i = 0; i < 4; ++i) {
    int t = tile * 64 + i * 16 + ty;
    float* p = part + ((size_t)split * N_TOK + t) * 64;
#pragma unroll
    for (int j = 0; j < 4; ++j) p[16 * j + tx] = acc[i][j];
  }
}

// ---------------------------------------------------------------------------
// Epilogue: one token per thread. Sum split partials -> 64 logits in regs.
// top-2 (lax.top_k tie-break = lowest index first), gates, lse, probs.
// ---------------------------------------------------------------------------
__global__ __launch_bounds__(256)
void epilogue(const float* __restrict__ part, int nsplit,
              float* __restrict__ out,             // d_out base (float)
              double* __restrict__ p_sum_d,
              unsigned* __restrict__ freq,
              double* __restrict__ lsesq_d) {
  const int tid  = threadIdx.x;
  const int t    = blockIdx.x * 256 + tid;
  const int lane = tid & 63;
  const int wv   = tid >> 6;

  float l[64];
  {
    const float* p0 = part + (size_t)t * 64;
#pragma unroll
    for (int q = 0; q < 16; ++q) {
      float4 a = *(const float4*)(p0 + q * 4);
      l[q * 4 + 0] = a.x; l[q * 4 + 1] = a.y;
      l[q * 4 + 2] = a.z; l[q * 4 + 3] = a.w;
    }
  }
  for (int s = 1; s < nsplit; ++s) {
    const float* ps = part + ((size_t)s * N_TOK + t) * 64;
#pragma unroll
    for (int q = 0; q < 16; ++q) {
      float4 a = *(const float4*)(ps + q * 4);
      l[q * 4 + 0] += a.x; l[q * 4 + 1] += a.y;
      l[q * 4 + 2] += a.z; l[q * 4 + 3] += a.w;
    }
  }

  // row max
  float m = l[0];
#pragma unroll
  for (int e = 1; e < 64; ++e) m = fmaxf(m, l[e]);

  // exp sum
  float sum = 0.f;
#pragma unroll
  for (int e = 0; e < 64; ++e) sum += __expf(l[e] - m);
  const float lse = m + __logf(sum);
  const float inv = 1.0f / sum;

  // top-2 scan, strict > keeps lowest index on ties (lax.top_k semantics)
  float v0 = l[0], v1 = -3.402823466e38f;
  int i0 = 0, i1 = 0;
#pragma unroll
  for (int e = 1; e < 64; ++e) {
    float le = l[e];
    bool g0 = le > v0;
    bool g1 = le > v1;
    // if g0: shift; elif g1: replace second
    float nv1 = g0 ? v0 : (g1 ? le : v1);
    int   ni1 = g0 ? i0 : (g1 ? e  : i1);
    float nv0 = g0 ? le : v0;
    int   ni0 = g0 ? e  : i0;
    v0 = nv0; i0 = ni0; v1 = nv1; i1 = ni1;
  }

  // gates = softmax([v0, v1])
  float d  = __expf(v1 - v0);
  float g0 = 1.0f / (1.0f + d);
  float g1 = d * g0;

  out[t * 2 + 0] = (float)i0;
  out[t * 2 + 1] = (float)i1;
  out[2 * N_TOK + t * 2 + 0] = g0;
  out[2 * N_TOK + t * 2 + 1] = g1;

  // ---- freq histogram (exact ints) ----
  __shared__ unsigned hist[64];
  if (tid < 64) hist[tid] = 0u;
  __syncthreads();
  atomicAdd(&hist[i0], 1u);
  atomicAdd(&hist[i1], 1u);

  // ---- p_sum: wave butterfly per expert ----
  float myps = 0.f;
#pragma unroll
  for (int e = 0; e < 64; ++e) {
    float v = __expf(l[e] - m) * inv;
    v += __shfl_xor(v, 32, 64);
    v += __shfl_xor(v, 16, 64);
    v += __shfl_xor(v, 8, 64);
    v += __shfl_xor(v, 4, 64);
    v += __shfl_xor(v, 2, 64);
    v += __shfl_xor(v, 1, 64);
    myps = (lane == e) ? v : myps;
  }

  __shared__ float s_ps[4][64];
  s_ps[wv][lane] = myps;

  // ---- lse^2 wave reduce ----
  float z = lse * lse;
  z += __shfl_xor(z, 32, 64);
  z += __shfl_xor(z, 16, 64);
  z += __shfl_xor(z, 8, 64);
  z += __shfl_xor(z, 4, 64);
  z += __shfl_xor(z, 2, 64);
  z += __shfl_xor(z, 1, 64);
  __shared__ double s_z[4];
  if (lane == 0) s_z[wv] = (double)z;

  __syncthreads();
  if (tid < 64) {
    float tot = s_ps[0][tid] + s_ps[1][tid] + s_ps[2][tid] + s_ps[3][tid];
    atomicAdd(&p_sum_d[tid], (double)tot);
    atomicAdd(&freq[tid], hist[tid]);
  }
  if (tid == 0) {
    atomicAdd(lsesq_d, s_z[0] + s_z[1] + s_z[2] + s_z[3]);
  }
}

// ---------------------------------------------------------------------------
// Finalize: switchloss + 0.1 * z_loss  (1 block, 64 threads)
// ---------------------------------------------------------------------------
__global__ void finalize(const double* __restrict__ p_sum_d,
                         const unsigned* __restrict__ freq,
                         const double* __restrict__ lsesq_d,
                         float* __restrict__ out_loss) {
  const int lane = threadIdx.x;
  double p = p_sum_d[lane];
  double f = (double)freq[lane];

  double pa = fabs(p);
  double fa = fabs(f);
#pragma unroll
  for (int off = 32; off >= 1; off >>= 1) {
    pa += __shfl_xor(pa, off, 64);
    fa += __shfl_xor(fa, off, 64);
  }
  pa = pa > 1e-12 ? pa : 1e-12;
  fa = fa > 1e-12 ? fa : 1e-12;

  double s = (p / pa) * (f / fa);
#pragma unroll
  for (int off = 32; off >= 1; off >>= 1) s += __shfl_xor(s, off, 64);

  if (lane == 0) {
    double switchloss = 64.0 * s;
    double z_loss = lsesq_d[0] / (double)N_TOK;
    out_loss[0] = (float)(switchloss + 0.1 * z_loss);
  }
}

extern "C" void kernel_launch(void* const* d_in, const int* in_sizes, int n_in,
                              void* d_out, int out_size, void* d_ws, size_t ws_size,
                              hipStream_t stream) {
  const float* x = (const float*)d_in[0];
  const float* W = (const float*)d_in[1];
  float* out = (float*)d_out;

  const size_t partB = (size_t)N_TOK * 64 * 4;  // 4 MB per split
  int S = 4;
  while (S > 1 && (size_t)S * partB + 4096 > ws_size) S >>= 1;

  float* part = (float*)d_ws;
  size_t tail = ((size_t)S * partB + 511) & ~(size_t)511;
  double* p_sum_d = (double*)((char*)d_ws + tail);
  double* lsesq_d = p_sum_d + 64;
  unsigned* freq  = (unsigned*)(lsesq_d + 1);

  hipMemsetAsync((char*)d_ws + tail, 0, 64 * 8 + 8 + 64 * 4, stream);

  router_gemm<<<NTILES * S, 256, 0, stream>>>(x, W, part, S, D_DIM / S);
  epilogue<<<N_TOK / 256, 256, 0, stream>>>(part, S, out, p_sum_d, freq, lsesq_d);
  finalize<<<1, 64, 0, stream>>>(p_sum_d, freq, lsesq_d, out + 4 * N_TOK);
}